// Round 4
// baseline (477.227 us; speedup 1.0000x reference)
//
#include <hip/hip_runtime.h>

#define T_TOKENS 2048
#define HIDDEN   2048
#define NEXPERT  32
#define TOPK     4
#define INTER    768
#define NPAIRS   (T_TOKENS*TOPK)   /* 8192 */
#define BM       128
#define BK       32
#define MT_MAX   95                /* sum ceil(cnt/128) <= 64 + 31 */
#define NT1      24                /* 768/32 gated col-tiles (BN=64: 32 g + 32 u) */
#define NT2      32                /* 2048/64 out col-tiles */
#define NK1      (HIDDEN/BK)       /* 64 */
#define NK2      (INTER/BK)        /* 24 */

typedef short  bh8 __attribute__((ext_vector_type(8)));   // 8 bf16
typedef float  fx4 __attribute__((ext_vector_type(4)));

#define AS1 __attribute__((address_space(1)))
#define AS3 __attribute__((address_space(3)))

__device__ __forceinline__ void gload_lds16(const void* g, const void* lds_generic){
    __builtin_amdgcn_global_load_lds(
        (const AS1 void*)(unsigned long long)g,
        (AS3 void*)(unsigned int)(unsigned long long)lds_generic,
        16, 0, 0);
}

// pack two f32 -> two bf16 (round-half-up: 2 adds + 1 v_perm); lo=first arg
__device__ __forceinline__ unsigned int pack2bf(float a, float b){
    unsigned ua = __float_as_uint(a) + 0x8000u;
    unsigned ub = __float_as_uint(b) + 0x8000u;
    return __builtin_amdgcn_perm(ub, ua, 0x07060302u);
}
__device__ __forceinline__ unsigned short f2bfu(float f){
    return (unsigned short)((__float_as_uint(f) + 0x8000u) >> 16);
}

/* ---------------- x -> bf16 ---------------- */
__global__ void cvt_x_k(const float* __restrict__ x, unsigned short* __restrict__ xb){
    int i = (blockIdx.x*256 + threadIdx.x)*8;
    float4 a = *(const float4*)(x+i);
    float4 b = *(const float4*)(x+i+4);
    uint4 o;
    o.x = pack2bf(a.x,a.y); o.y = pack2bf(a.z,a.w);
    o.z = pack2bf(b.x,b.y); o.w = pack2bf(b.z,b.w);
    *(uint4*)(xb+i) = o;
}

/* ---------------- router ---------------- */
__global__ void router_k(const float* __restrict__ x, const float* __restrict__ gate,
                         int* __restrict__ topk_id, float* __restrict__ topk_w,
                         int* __restrict__ counts){
    const int t = blockIdx.x;
    const int l = threadIdx.x;
    const float* xr = x + (size_t)t*HIDDEN;
    float acc[NEXPERT];
#pragma unroll
    for (int e=0;e<NEXPERT;e++) acc[e]=0.f;
    for (int d=l; d<HIDDEN; d+=64){
        float xv = xr[d];
        const float4* g4 = (const float4*)(gate + (size_t)d*NEXPERT);
#pragma unroll
        for (int i=0;i<8;i++){
            float4 g = g4[i];
            acc[i*4+0] += xv*g.x; acc[i*4+1] += xv*g.y;
            acc[i*4+2] += xv*g.z; acc[i*4+3] += xv*g.w;
        }
    }
#pragma unroll
    for (int e=0;e<NEXPERT;e++){
#pragma unroll
        for (int m=1;m<64;m<<=1) acc[e] += __shfl_xor(acc[e], m, 64);
    }
    int ids[TOPK]; float lv[TOPK];
#pragma unroll
    for (int k=0;k<TOPK;k++){
        float m=-1e30f; int mi=0;
#pragma unroll
        for (int e=0;e<NEXPERT;e++){ if (acc[e]>m){ m=acc[e]; mi=e; } }
        ids[k]=mi; lv[k]=m; acc[mi]=-1e30f;
    }
    float ex[TOPK]; float s=0.f;
#pragma unroll
    for (int k=0;k<TOPK;k++){ ex[k]=__expf(lv[k]-lv[0]); s+=ex[k]; }
    if (l==0){
        float inv = 1.f/s;
#pragma unroll
        for (int k=0;k<TOPK;k++){
            topk_id[t*TOPK+k]=ids[k];
            topk_w[t*TOPK+k]=ex[k]*inv;
            atomicAdd(&counts[ids[k]],1);
        }
    }
}

/* ---------------- schedule ---------------- */
__global__ void sched_k(const int* __restrict__ counts, int* __restrict__ offs,
                        int* __restrict__ cursors, int* __restrict__ nmt,
                        int* __restrict__ te, int* __restrict__ tr0, int* __restrict__ trn){
    if (threadIdx.x==0 && blockIdx.x==0){
        int tot=0, nm=0;
        for (int e=0;e<NEXPERT;e++){
            int c = counts[e];
            offs[e]=tot; cursors[e]=tot;
            for (int s=0;s<c;s+=BM){
                te[nm]=e; tr0[nm]=tot+s; trn[nm]=(c-s)<BM?(c-s):BM; nm++;
            }
            tot+=c;
        }
        *nmt = nm;
    }
}

/* ---------------- scatter ---------------- */
__global__ void scatter_k(const int* __restrict__ topk_id, const float* __restrict__ topk_w,
                          int* __restrict__ cursors, int* __restrict__ pair_tok,
                          float* __restrict__ pair_w){
    int g = blockIdx.x*256 + threadIdx.x;
    int e = topk_id[g];
    float w = topk_w[g];
    int pos = atomicAdd(&cursors[e],1);
    pair_tok[pos] = g>>2;
    pair_w[pos]  = w;
}

/* tile-id decode: bijective XCD-chunked swizzle, mt innermost */
#define TILE_DECODE(NT)                                            \
    const int nwg = gridDim.x;                                     \
    const int q = nwg>>3, r = nwg&7;                               \
    const int xcd = blockIdx.x & 7, bidx = blockIdx.x >> 3;        \
    const int L = (xcd<r ? xcd*(q+1) : r*(q+1)+(xcd-r)*q) + bidx;  \
    const int mt = L % MT_MAX, nt = L / MT_MAX;                    \
    if (mt >= *nmt) return;                                        \
    const int e = te[mt], row0 = tr0[mt], rows = trn[mt];

/* one K-step, counted-vmcnt pipeline.
   Entry: As[C0],Bs[C0] valid; RW holds raw B(KK+1); in-flight: A(KK+1) DMA (+prev 4-group).
   Issues A(KK+2)->As[C2] DMA + B(KK+2)->RL (4 vmem); computes KK; vmcnt(4) leaves
   exactly those 4; ds_write B(KK+1)->Bs[C1]; lgkmcnt(0); raw barrier. */
#define GSTEP(KK, NK, BSTR, C0, C1, C2, RL0, RL1, RW0, RW1) do{                 \
    int _ks = (KK)+2; if (_ks > (NK)-1) _ks = (NK)-1;                           \
    const float* _bp = bsrc + (size_t)_ks*BK*(BSTR);                            \
    RL0 = *(const float4*)(_bp);                                                \
    RL1 = *(const float4*)(_bp + (BSTR));                                       \
    gload_lds16(asrc0 + _ks*BK, &As[C2][(w*16)*32]);                            \
    gload_lds16(asrc1 + _ks*BK, &As[C2][(64+w*16)*32]);                         \
    {   const unsigned short* _Ak = As[C0];                                     \
        const char* _Bk = (const char*)Bs[C0];                                  \
        bh8 _a0 = *(const bh8*)(_Ak + (w*32+l15)*32    + ((kb^sA)<<3));         \
        bh8 _a1 = *(const bh8*)(_Ak + (w*32+16+l15)*32 + ((kb^sA)<<3));         \
        _Pragma("unroll")                                                       \
        for (int c=0;c<4;c++){                                                  \
            const int bc = c*16 + l15;                                          \
            bh8 _b = *(const bh8*)(_Bk + bc*80 + ((kb ^ ((bc>>3)&3))<<4));      \
            acc[0][c] = __builtin_amdgcn_mfma_f32_16x16x32_bf16(_a0,_b,acc[0][c],0,0,0); \
            acc[1][c] = __builtin_amdgcn_mfma_f32_16x16x32_bf16(_a1,_b,acc[1][c],0,0,0); \
        }                                                                       \
    }                                                                           \
    asm volatile("s_waitcnt vmcnt(4)" ::: "memory");                            \
    {   char* _bw = (char*)Bs[C1];                                              \
        *(unsigned*)(_bw + wb      ) = pack2bf(RW0.x, RW1.x);                   \
        *(unsigned*)(_bw + wb +  80) = pack2bf(RW0.y, RW1.y);                   \
        *(unsigned*)(_bw + wb + 160) = pack2bf(RW0.z, RW1.z);                   \
        *(unsigned*)(_bw + wb + 240) = pack2bf(RW0.w, RW1.w);                   \
    }                                                                           \
    asm volatile("s_waitcnt lgkmcnt(0)" ::: "memory");                          \
    __builtin_amdgcn_s_barrier();                                               \
}while(0)

/* ============== grouped GEMM1: xb(bf16) x gup(f32->bf16) -> gated(bf16) ============== */
__global__ __launch_bounds__(256) void gemm1_k(
        const unsigned short* __restrict__ xb, const float* __restrict__ gup,
        const int* __restrict__ nmt, const int* __restrict__ te,
        const int* __restrict__ tr0, const int* __restrict__ trn,
        const int* __restrict__ pair_tok, const float* __restrict__ pair_w,
        unsigned short* __restrict__ gated){
    __shared__ __align__(16) unsigned short As[3][BM*32]; // 3 x 8KB
    __shared__ __align__(16) unsigned short Bs[3][64*40]; // 3 x 5KB
    __shared__ int   s_tok[BM];
    __shared__ float s_w[BM];

    TILE_DECODE(NT1)
    const int n0 = nt*32;

    const int t = threadIdx.x;
    if (t < BM){
        int p = row0 + t; if (p > NPAIRS-1) p = NPAIRS-1;
        s_tok[t] = pair_tok[p];
        s_w[t]   = pair_w[p];
    }
    __syncthreads();

    const int w = t>>6, lane = t&63;
    const int l15 = lane & 15, kb = lane >> 4;
    const int sA = (l15>>1)&3;

    const int arow0 = w*16 + (lane>>2);
    const int arow1 = 64 + arow0;
    const int ck0 = (lane&3) ^ ((lane>>3)&3);
    const unsigned short* asrc0 = xb + (size_t)s_tok[arow0]*HIDDEN + ck0*8;
    const unsigned short* asrc1 = xb + (size_t)s_tok[arow1]*HIDDEN + ck0*8;

    const int col4 = (t&15)*4;
    const int bd0  = (t>>4)*2;
    const int sB   = (col4>>3)&3;
    const unsigned wb = (unsigned)(col4*80 + (((bd0>>3) ^ sB)<<4) + (bd0&7)*2);
    const int fc = (col4 < 32) ? (n0 + col4) : (736 + n0 + col4);
    const float* bsrc = gup + (size_t)e*HIDDEN*(2*INTER) + (size_t)bd0*(2*INTER) + fc;

    fx4 acc[2][4];
#pragma unroll
    for (int i=0;i<2;i++)
#pragma unroll
        for (int j=0;j<4;j++) acc[i][j] = (fx4)0.f;

    float4 rE0, rE1, rO0, rO1;
    // prologue: A0,A1 DMA; B0->E, B1->O; full drain (once); write B0
    gload_lds16(asrc0,      &As[0][(w*16)*32]);
    gload_lds16(asrc1,      &As[0][(64+w*16)*32]);
    gload_lds16(asrc0 + BK, &As[1][(w*16)*32]);
    gload_lds16(asrc1 + BK, &As[1][(64+w*16)*32]);
    rE0 = *(const float4*)(bsrc);
    rE1 = *(const float4*)(bsrc + 2*INTER);
    rO0 = *(const float4*)(bsrc + (size_t)BK*2*INTER);
    rO1 = *(const float4*)(bsrc + (size_t)BK*2*INTER + 2*INTER);
    asm volatile("s_waitcnt vmcnt(0)" ::: "memory");
    {
        char* bw0 = (char*)Bs[0];
        *(unsigned*)(bw0 + wb      ) = pack2bf(rE0.x, rE1.x);
        *(unsigned*)(bw0 + wb +  80) = pack2bf(rE0.y, rE1.y);
        *(unsigned*)(bw0 + wb + 160) = pack2bf(rE0.z, rE1.z);
        *(unsigned*)(bw0 + wb + 240) = pack2bf(rE0.w, rE1.w);
    }
    asm volatile("s_waitcnt lgkmcnt(0)" ::: "memory");
    __builtin_amdgcn_s_barrier();

    int c0 = 0;
    for (int k2 = 0; k2 < NK1; k2 += 2){
        int c1 = c0+1; if (c1==3) c1 = 0;
        int c2 = c1+1; if (c2==3) c2 = 0;
        GSTEP(k2,   NK1, 2*INTER, c0, c1, c2, rE0, rE1, rO0, rO1);
        GSTEP(k2+1, NK1, 2*INTER, c1, c2, c0, rO0, rO1, rE0, rE1);
        c0 = c2;
    }
    asm volatile("s_waitcnt vmcnt(0)" ::: "memory");

    // epilogue: gated = silu(g)*u*router_w (32 cols: c=0,1 gate / c=2,3 up)
    const int rbase = w*32 + kb*4;
#pragma unroll
    for (int mr=0;mr<2;mr++){
#pragma unroll
        for (int qq=0;qq<4;qq++){
            int row = rbase + mr*16 + qq;
            if (row < rows){
                float wgt = s_w[row];
                size_t prow = (size_t)(row0 + row)*INTER + n0 + l15;
#pragma unroll
                for (int c=0;c<2;c++){
                    float g = acc[mr][c][qq], u = acc[mr][c+2][qq];
                    float sil = g / (1.f + __expf(-g));
                    gated[prow + c*16] = f2bfu(sil*u*wgt);
                }
            }
        }
    }
}

/* ============== grouped GEMM2: gated(bf16) x down(f32->bf16) -> out (atomic f32) ============== */
__global__ __launch_bounds__(256) void gemm2_k(
        const unsigned short* __restrict__ gated, const float* __restrict__ down,
        const int* __restrict__ nmt, const int* __restrict__ te,
        const int* __restrict__ tr0, const int* __restrict__ trn,
        const int* __restrict__ pair_tok, float* __restrict__ out){
    __shared__ __align__(16) unsigned short As[3][BM*32];
    __shared__ __align__(16) unsigned short Bs[3][64*40];
    __shared__ int s_tok[BM];

    TILE_DECODE(NT2)
    const int n0 = nt*64;

    const int t = threadIdx.x;
    if (t < BM){
        int p = row0 + t; if (p > NPAIRS-1) p = NPAIRS-1;
        s_tok[t] = pair_tok[p];
    }
    __syncthreads();

    const int w = t>>6, lane = t&63;
    const int l15 = lane & 15, kb = lane >> 4;
    const int sA = (l15>>1)&3;

    const int arow0 = w*16 + (lane>>2);
    const int arow1 = 64 + arow0;
    const int ck0 = (lane&3) ^ ((lane>>3)&3);
    int ap0 = row0 + arow0; if (ap0 > NPAIRS-1) ap0 = NPAIRS-1;
    int ap1 = row0 + arow1; if (ap1 > NPAIRS-1) ap1 = NPAIRS-1;
    const unsigned short* asrc0 = gated + (size_t)ap0*INTER + ck0*8;
    const unsigned short* asrc1 = gated + (size_t)ap1*INTER + ck0*8;

    const int col4 = (t&15)*4;
    const int bd0  = (t>>4)*2;
    const int sB   = (col4>>3)&3;
    const unsigned wb = (unsigned)(col4*80 + (((bd0>>3) ^ sB)<<4) + (bd0&7)*2);
    const float* bsrc = down + (size_t)e*INTER*HIDDEN + (size_t)bd0*HIDDEN + (n0 + col4);

    fx4 acc[2][4];
#pragma unroll
    for (int i=0;i<2;i++)
#pragma unroll
        for (int j=0;j<4;j++) acc[i][j] = (fx4)0.f;

    float4 rE0, rE1, rO0, rO1;
    gload_lds16(asrc0,      &As[0][(w*16)*32]);
    gload_lds16(asrc1,      &As[0][(64+w*16)*32]);
    gload_lds16(asrc0 + BK, &As[1][(w*16)*32]);
    gload_lds16(asrc1 + BK, &As[1][(64+w*16)*32]);
    rE0 = *(const float4*)(bsrc);
    rE1 = *(const float4*)(bsrc + HIDDEN);
    rO0 = *(const float4*)(bsrc + (size_t)BK*HIDDEN);
    rO1 = *(const float4*)(bsrc + (size_t)BK*HIDDEN + HIDDEN);
    asm volatile("s_waitcnt vmcnt(0)" ::: "memory");
    {
        char* bw0 = (char*)Bs[0];
        *(unsigned*)(bw0 + wb      ) = pack2bf(rE0.x, rE1.x);
        *(unsigned*)(bw0 + wb +  80) = pack2bf(rE0.y, rE1.y);
        *(unsigned*)(bw0 + wb + 160) = pack2bf(rE0.z, rE1.z);
        *(unsigned*)(bw0 + wb + 240) = pack2bf(rE0.w, rE1.w);
    }
    asm volatile("s_waitcnt lgkmcnt(0)" ::: "memory");
    __builtin_amdgcn_s_barrier();

    int c0 = 0;
    for (int k2 = 0; k2 < NK2; k2 += 2){
        int c1 = c0+1; if (c1==3) c1 = 0;
        int c2 = c1+1; if (c2==3) c2 = 0;
        GSTEP(k2,   NK2, HIDDEN, c0, c1, c2, rE0, rE1, rO0, rO1);
        GSTEP(k2+1, NK2, HIDDEN, c1, c2, c0, rO0, rO1, rE0, rE1);
        c0 = c2;
    }
    asm volatile("s_waitcnt vmcnt(0)" ::: "memory");

    const int rbase = w*32 + kb*4;
#pragma unroll
    for (int mr=0;mr<2;mr++){
#pragma unroll
        for (int qq=0;qq<4;qq++){
            int row = rbase + mr*16 + qq;
            if (row < rows){
                float* orow = out + (size_t)s_tok[row]*HIDDEN + n0 + l15;
#pragma unroll
                for (int c=0;c<4;c++)
                    atomicAdd(orow + c*16, acc[mr][c][qq]);
            }
        }
    }
}

/* ---------------- host launch ---------------- */
extern "C" void kernel_launch(void* const* d_in, const int* in_sizes, int n_in,
                              void* d_out, int out_size, void* d_ws, size_t ws_size,
                              hipStream_t stream){
    const float* x    = (const float*)d_in[0];
    const float* gate = (const float*)d_in[1];
    const float* gup  = (const float*)d_in[2];
    const float* down = (const float*)d_in[3];
    float* out = (float*)d_out;
    char*  ws  = (char*)d_ws;

    int*   topk_id  = (int*)  (ws + 0x00000);
    float* topk_w   = (float*)(ws + 0x08000);
    int*   counts   = (int*)  (ws + 0x10000);
    int*   cursors  = (int*)  (ws + 0x10080);
    int*   offs     = (int*)  (ws + 0x10100);
    int*   nmt      = (int*)  (ws + 0x10180);
    int*   te       = (int*)  (ws + 0x10200);
    int*   tr0      = (int*)  (ws + 0x10400);
    int*   trn      = (int*)  (ws + 0x10600);
    int*   pair_tok = (int*)  (ws + 0x10800);
    float* pair_w   = (float*)(ws + 0x18800);
    unsigned short* gated = (unsigned short*)(ws + 0x21000);    // 8192*768*2 = 12.6MB
    unsigned short* xb    = (unsigned short*)(ws + 0xC60000);   // 2048*2048*2 = 8MB (+64B tail pad used by clamped over-reads stays in-bounds: reads clamp to last tile)

    hipMemsetAsync(d_out, 0, (size_t)out_size*sizeof(float), stream);
    hipMemsetAsync(counts, 0, NEXPERT*sizeof(int), stream);

    cvt_x_k  <<<T_TOKENS*HIDDEN/(256*8), 256, 0, stream>>>(x, xb);
    router_k <<<T_TOKENS, 64, 0, stream>>>(x, gate, topk_id, topk_w, counts);
    sched_k  <<<1, 64, 0, stream>>>(counts, offs, cursors, nmt, te, tr0, trn);
    scatter_k<<<NPAIRS/256, 256, 0, stream>>>(topk_id, topk_w, cursors, pair_tok, pair_w);
    gemm1_k  <<<MT_MAX*NT1, 256, 0, stream>>>(xb, gup, nmt, te, tr0, trn, pair_tok, pair_w, gated);
    gemm2_k  <<<MT_MAX*NT2, 256, 0, stream>>>(gated, down, nmt, te, tr0, trn, pair_tok, out);
}

// Round 5
// 448.201 us; speedup vs baseline: 1.0648x; 1.0648x over previous
//
#include <hip/hip_runtime.h>

#define T_TOKENS 2048
#define HIDDEN   2048
#define NEXPERT  32
#define TOPK     4
#define INTER    768
#define NPAIRS   (T_TOKENS*TOPK)   /* 8192 */
#define BM       128
#define BK       32
#define MT_MAX   95                /* sum ceil(cnt/128) <= 64 + 31 */
#define NT1      12                /* 1536/128 gate+up col-tiles (64 g + 64 u per tile) */
#define NT2      16                /* 2048/128 out col-tiles */
#define NK1      (HIDDEN/BK)       /* 64 */
#define NK2      (INTER/BK)        /* 24 */

typedef short  bh8 __attribute__((ext_vector_type(8)));   // 8 bf16
typedef float  fx4 __attribute__((ext_vector_type(4)));

#define AS1 __attribute__((address_space(1)))
#define AS3 __attribute__((address_space(3)))

__device__ __forceinline__ void gload_lds16(const void* g, const void* lds_generic){
    __builtin_amdgcn_global_load_lds(
        (const AS1 void*)(unsigned long long)g,
        (AS3 void*)(unsigned int)(unsigned long long)lds_generic,
        16, 0, 0);
}

// pack two f32 -> two bf16 (round-half-up: 2 adds + 1 v_perm); result shorts [a,b]
__device__ __forceinline__ unsigned int pack2bf(float a, float b){
    unsigned ua = __float_as_uint(a) + 0x8000u;
    unsigned ub = __float_as_uint(b) + 0x8000u;
    return __builtin_amdgcn_perm(ub, ua, 0x07060302u);
}
__device__ __forceinline__ unsigned short f2bfu(float f){
    return (unsigned short)((__float_as_uint(f) + 0x8000u) >> 16);
}

/* ---------------- x -> bf16 ---------------- */
__global__ void cvt_x_k(const float* __restrict__ x, unsigned short* __restrict__ xb){
    int i = (blockIdx.x*256 + threadIdx.x)*8;
    float4 a = *(const float4*)(x+i);
    float4 b = *(const float4*)(x+i+4);
    uint4 o;
    o.x = pack2bf(a.x,a.y); o.y = pack2bf(a.z,a.w);
    o.z = pack2bf(b.x,b.y); o.w = pack2bf(b.z,b.w);
    *(uint4*)(xb+i) = o;
}

/* ---------------- router ---------------- */
__global__ void router_k(const float* __restrict__ x, const float* __restrict__ gate,
                         int* __restrict__ topk_id, float* __restrict__ topk_w,
                         int* __restrict__ counts){
    const int t = blockIdx.x;
    const int l = threadIdx.x;
    const float* xr = x + (size_t)t*HIDDEN;
    float acc[NEXPERT];
#pragma unroll
    for (int e=0;e<NEXPERT;e++) acc[e]=0.f;
    for (int d=l; d<HIDDEN; d+=64){
        float xv = xr[d];
        const float4* g4 = (const float4*)(gate + (size_t)d*NEXPERT);
#pragma unroll
        for (int i=0;i<8;i++){
            float4 g = g4[i];
            acc[i*4+0] += xv*g.x; acc[i*4+1] += xv*g.y;
            acc[i*4+2] += xv*g.z; acc[i*4+3] += xv*g.w;
        }
    }
#pragma unroll
    for (int e=0;e<NEXPERT;e++){
#pragma unroll
        for (int m=1;m<64;m<<=1) acc[e] += __shfl_xor(acc[e], m, 64);
    }
    int ids[TOPK]; float lv[TOPK];
#pragma unroll
    for (int k=0;k<TOPK;k++){
        float m=-1e30f; int mi=0;
#pragma unroll
        for (int e=0;e<NEXPERT;e++){ if (acc[e]>m){ m=acc[e]; mi=e; } }
        ids[k]=mi; lv[k]=m; acc[mi]=-1e30f;
    }
    float ex[TOPK]; float s=0.f;
#pragma unroll
    for (int k=0;k<TOPK;k++){ ex[k]=__expf(lv[k]-lv[0]); s+=ex[k]; }
    if (l==0){
        float inv = 1.f/s;
#pragma unroll
        for (int k=0;k<TOPK;k++){
            topk_id[t*TOPK+k]=ids[k];
            topk_w[t*TOPK+k]=ex[k]*inv;
            atomicAdd(&counts[ids[k]],1);
        }
    }
}

/* ---------------- schedule ---------------- */
__global__ void sched_k(const int* __restrict__ counts, int* __restrict__ offs,
                        int* __restrict__ cursors, int* __restrict__ nmt,
                        int* __restrict__ te, int* __restrict__ tr0, int* __restrict__ trn){
    if (threadIdx.x==0 && blockIdx.x==0){
        int tot=0, nm=0;
        for (int e=0;e<NEXPERT;e++){
            int c = counts[e];
            offs[e]=tot; cursors[e]=tot;
            for (int s=0;s<c;s+=BM){
                te[nm]=e; tr0[nm]=tot+s; trn[nm]=(c-s)<BM?(c-s):BM; nm++;
            }
            tot+=c;
        }
        *nmt = nm;
    }
}

/* ---------------- scatter ---------------- */
__global__ void scatter_k(const int* __restrict__ topk_id, const float* __restrict__ topk_w,
                          int* __restrict__ cursors, int* __restrict__ pair_tok,
                          float* __restrict__ pair_w){
    int g = blockIdx.x*256 + threadIdx.x;
    int e = topk_id[g];
    float w = topk_w[g];
    int pos = atomicAdd(&cursors[e],1);
    pair_tok[pos] = g>>2;
    pair_w[pos]  = w;
}

/* tile-id decode: bijective XCD-chunked swizzle, mt innermost */
#define TILE_DECODE(NT)                                            \
    const int nwg = gridDim.x;                                     \
    const int q = nwg>>3, r = nwg&7;                               \
    const int xcd = blockIdx.x & 7, bidx = blockIdx.x >> 3;        \
    const int L = (xcd<r ? xcd*(q+1) : r*(q+1)+(xcd-r)*q) + bidx;  \
    const int mt = L % MT_MAX, nt = L / MT_MAX;                    \
    if (mt >= *nmt) return;                                        \
    const int e = te[mt], row0 = tr0[mt], rows = trn[mt];

/* one K-step, prefetch distance 3, counted vmcnt(12).
   At step k: issue B(k+3)->reg set I* + A(k+3) DMA -> As[aW]; compute step k
   from As[aR],Bs[bRd]; vmcnt(12) retires step k-2's 6 ops (B(k+1) regs W*,
   A(k+1) DMA); ds_write Bs[bRd^1] <- W*; lgkmcnt(0); barrier. */
#define PSTEP(KK, NK, BSTR, I0,I1,I2,I3, W0,W1,W2,W3) do{                       \
    int _ks = (KK)+3; if (_ks > (NK)-1) _ks = (NK)-1;                           \
    const float* _bp = bsrc + (size_t)_ks*BK*(BSTR);                            \
    I0 = *(const float4*)(_bp);                                                 \
    I1 = *(const float4*)(_bp + (BSTR));                                        \
    I2 = *(const float4*)(_bp + 2*(BSTR));                                      \
    I3 = *(const float4*)(_bp + 3*(BSTR));                                      \
    gload_lds16(asrc0 + _ks*BK, &As[aW][(w*16)*32]);                            \
    gload_lds16(asrc1 + _ks*BK, &As[aW][(64+w*16)*32]);                         \
    {   const unsigned short* _Ak = As[aR];                                     \
        const char* _Bk = (const char*)Bs[bRd];                                 \
        bh8 _a0 = *(const bh8*)(_Ak + (w*32+l15)*32    + ((kb^sA)<<3));         \
        bh8 _a1 = *(const bh8*)(_Ak + (w*32+16+l15)*32 + ((kb^sA)<<3));         \
        _Pragma("unroll")                                                       \
        for (int c=0;c<8;c++){                                                  \
            const int bc = c*16 + l15;                                          \
            bh8 _b = *(const bh8*)(_Bk + bc*80 + ((kb ^ ((bc>>3)&3))<<4));      \
            acc[0][c] = __builtin_amdgcn_mfma_f32_16x16x32_bf16(_a0,_b,acc[0][c],0,0,0); \
            acc[1][c] = __builtin_amdgcn_mfma_f32_16x16x32_bf16(_a1,_b,acc[1][c],0,0,0); \
        }                                                                       \
    }                                                                           \
    asm volatile("s_waitcnt vmcnt(12)" ::: "memory");                           \
    {   char* _bw = (char*)Bs[bRd^1];                                           \
        *(uint2*)(_bw + wb      ) = make_uint2(pack2bf(W0.x,W1.x), pack2bf(W2.x,W3.x)); \
        *(uint2*)(_bw + wb +  80) = make_uint2(pack2bf(W0.y,W1.y), pack2bf(W2.y,W3.y)); \
        *(uint2*)(_bw + wb + 160) = make_uint2(pack2bf(W0.z,W1.z), pack2bf(W2.z,W3.z)); \
        *(uint2*)(_bw + wb + 240) = make_uint2(pack2bf(W0.w,W1.w), pack2bf(W2.w,W3.w)); \
    }                                                                           \
    asm volatile("s_waitcnt lgkmcnt(0)" ::: "memory");                          \
    __builtin_amdgcn_s_barrier();                                               \
    aR=(aR+1)&3; aW=(aW+1)&3; bRd^=1;                                           \
}while(0)

#define LDB(SET0,SET1,SET2,SET3, KS, BSTR) do{                                  \
    const float* _bp = bsrc + (size_t)(KS)*BK*(BSTR);                           \
    SET0 = *(const float4*)(_bp);                                               \
    SET1 = *(const float4*)(_bp + (BSTR));                                      \
    SET2 = *(const float4*)(_bp + 2*(BSTR));                                    \
    SET3 = *(const float4*)(_bp + 3*(BSTR));                                    \
}while(0)

#define WRB0(W0,W1,W2,W3) do{                                                   \
    char* _bw = (char*)Bs[0];                                                   \
    *(uint2*)(_bw + wb      ) = make_uint2(pack2bf(W0.x,W1.x), pack2bf(W2.x,W3.x)); \
    *(uint2*)(_bw + wb +  80) = make_uint2(pack2bf(W0.y,W1.y), pack2bf(W2.y,W3.y)); \
    *(uint2*)(_bw + wb + 160) = make_uint2(pack2bf(W0.z,W1.z), pack2bf(W2.z,W3.z)); \
    *(uint2*)(_bw + wb + 240) = make_uint2(pack2bf(W0.w,W1.w), pack2bf(W2.w,W3.w)); \
}while(0)

/* ============== grouped GEMM1: xb(bf16) x gup(f32->bf16) -> gated(bf16) ============== */
__global__ __launch_bounds__(256) void gemm1_k(
        const unsigned short* __restrict__ xb, const float* __restrict__ gup,
        const int* __restrict__ nmt, const int* __restrict__ te,
        const int* __restrict__ tr0, const int* __restrict__ trn,
        const int* __restrict__ pair_tok, const float* __restrict__ pair_w,
        unsigned short* __restrict__ gated){
    __shared__ __align__(16) unsigned short As[4][BM*32];   // 4 x 8KB, linear 64B rows
    __shared__ __align__(16) unsigned short Bs[2][128*40];  // 2 x 10KB, [col][40] pitch 80B
    __shared__ int   s_tok[BM];
    __shared__ float s_w[BM];

    TILE_DECODE(NT1)
    const int n0 = nt*64;

    const int t = threadIdx.x;
    if (t < BM){
        int p = row0 + t; if (p > NPAIRS-1) p = NPAIRS-1;
        s_tok[t] = pair_tok[p];
        s_w[t]   = pair_w[p];
    }
    __syncthreads();

    const int w = t>>6, lane = t&63;
    const int l15 = lane & 15, kb = lane >> 4;
    const int sA = (l15>>1)&3;

    // A DMA (gathered bf16 x rows)
    const int arow0 = w*16 + (lane>>2);
    const int arow1 = 64 + arow0;
    const int ck0 = (lane&3) ^ ((lane>>3)&3);
    const unsigned short* asrc0 = xb + (size_t)s_tok[arow0]*HIDDEN + ck0*8;
    const unsigned short* asrc1 = xb + (size_t)s_tok[arow1]*HIDDEN + ck0*8;

    // B staging: thread -> 4 cols x 4 k-rows
    const int j5 = t & 31, col4 = j5*4;
    const int bd0  = (t>>5)*4;
    const int gq = (j5>>1)&3;
    const unsigned wb = (unsigned)(col4*80 + (((bd0>>3) ^ gq)<<4) + (bd0&4)*2);
    const int fc = (col4 < 64) ? (n0 + col4) : (704 + n0 + col4);
    const float* bsrc = gup + (size_t)e*HIDDEN*(2*INTER) + (size_t)bd0*(2*INTER) + fc;

    fx4 acc[2][8];
#pragma unroll
    for (int i=0;i<2;i++)
#pragma unroll
        for (int j=0;j<8;j++) acc[i][j] = (fx4)0.f;

    float4 s0_0,s0_1,s0_2,s0_3, s1_0,s1_1,s1_2,s1_3, s2_0,s2_1,s2_2,s2_3;

    // prologue: sets 0..2 <- B(0..2); A(0..2) DMA -> As[0..2]
    LDB(s0_0,s0_1,s0_2,s0_3, 0, 2*INTER);
    gload_lds16(asrc0,        &As[0][(w*16)*32]);
    gload_lds16(asrc1,        &As[0][(64+w*16)*32]);
    LDB(s1_0,s1_1,s1_2,s1_3, 1, 2*INTER);
    gload_lds16(asrc0 + BK,   &As[1][(w*16)*32]);
    gload_lds16(asrc1 + BK,   &As[1][(64+w*16)*32]);
    LDB(s2_0,s2_1,s2_2,s2_3, 2, 2*INTER);
    gload_lds16(asrc0 + 2*BK, &As[2][(w*16)*32]);
    gload_lds16(asrc1 + 2*BK, &As[2][(64+w*16)*32]);
    asm volatile("s_waitcnt vmcnt(12)" ::: "memory");   // set0 + A(0) retired
    WRB0(s0_0,s0_1,s0_2,s0_3);
    asm volatile("s_waitcnt lgkmcnt(0)" ::: "memory");
    __builtin_amdgcn_s_barrier();

    int aR=0, aW=3, bRd=0;
    for (int k3=0; k3<NK1-1; k3+=3){
        PSTEP(k3,   NK1, 2*INTER, s0_0,s0_1,s0_2,s0_3, s1_0,s1_1,s1_2,s1_3);
        PSTEP(k3+1, NK1, 2*INTER, s1_0,s1_1,s1_2,s1_3, s2_0,s2_1,s2_2,s2_3);
        PSTEP(k3+2, NK1, 2*INTER, s2_0,s2_1,s2_2,s2_3, s0_0,s0_1,s0_2,s0_3);
    }
    PSTEP(NK1-1, NK1, 2*INTER, s0_0,s0_1,s0_2,s0_3, s1_0,s1_1,s1_2,s1_3);
    asm volatile("s_waitcnt vmcnt(0)" ::: "memory");

    // epilogue: gated = silu(g)*u*router_w (c=0..3 gate, c=4..7 up)
    const int rbase = w*32 + kb*4;
#pragma unroll
    for (int mr=0;mr<2;mr++){
#pragma unroll
        for (int qq=0;qq<4;qq++){
            int row = rbase + mr*16 + qq;
            if (row < rows){
                float wgt = s_w[row];
                size_t prow = (size_t)(row0 + row)*INTER + n0 + l15;
#pragma unroll
                for (int c=0;c<4;c++){
                    float g = acc[mr][c][qq], u = acc[mr][c+4][qq];
                    float sil = g / (1.f + __expf(-g));
                    gated[prow + c*16] = f2bfu(sil*u*wgt);
                }
            }
        }
    }
}

/* ============== grouped GEMM2: gated(bf16) x down(f32->bf16) -> out (atomic f32) ============== */
__global__ __launch_bounds__(256) void gemm2_k(
        const unsigned short* __restrict__ gated, const float* __restrict__ down,
        const int* __restrict__ nmt, const int* __restrict__ te,
        const int* __restrict__ tr0, const int* __restrict__ trn,
        const int* __restrict__ pair_tok, float* __restrict__ out){
    __shared__ __align__(16) unsigned short As[4][BM*32];
    __shared__ __align__(16) unsigned short Bs[2][128*40];
    __shared__ int s_tok[BM];

    TILE_DECODE(NT2)
    const int n0 = nt*128;

    const int t = threadIdx.x;
    if (t < BM){
        int p = row0 + t; if (p > NPAIRS-1) p = NPAIRS-1;
        s_tok[t] = pair_tok[p];
    }
    __syncthreads();

    const int w = t>>6, lane = t&63;
    const int l15 = lane & 15, kb = lane >> 4;
    const int sA = (l15>>1)&3;

    const int arow0 = w*16 + (lane>>2);
    const int arow1 = 64 + arow0;
    const int ck0 = (lane&3) ^ ((lane>>3)&3);
    int ap0 = row0 + arow0; if (ap0 > NPAIRS-1) ap0 = NPAIRS-1;
    int ap1 = row0 + arow1; if (ap1 > NPAIRS-1) ap1 = NPAIRS-1;
    const unsigned short* asrc0 = gated + (size_t)ap0*INTER + ck0*8;
    const unsigned short* asrc1 = gated + (size_t)ap1*INTER + ck0*8;

    const int j5 = t & 31, col4 = j5*4;
    const int bd0  = (t>>5)*4;
    const int gq = (j5>>1)&3;
    const unsigned wb = (unsigned)(col4*80 + (((bd0>>3) ^ gq)<<4) + (bd0&4)*2);
    const float* bsrc = down + (size_t)e*INTER*HIDDEN + (size_t)bd0*HIDDEN + (n0 + col4);

    fx4 acc[2][8];
#pragma unroll
    for (int i=0;i<2;i++)
#pragma unroll
        for (int j=0;j<8;j++) acc[i][j] = (fx4)0.f;

    float4 s0_0,s0_1,s0_2,s0_3, s1_0,s1_1,s1_2,s1_3, s2_0,s2_1,s2_2,s2_3;

    LDB(s0_0,s0_1,s0_2,s0_3, 0, HIDDEN);
    gload_lds16(asrc0,        &As[0][(w*16)*32]);
    gload_lds16(asrc1,        &As[0][(64+w*16)*32]);
    LDB(s1_0,s1_1,s1_2,s1_3, 1, HIDDEN);
    gload_lds16(asrc0 + BK,   &As[1][(w*16)*32]);
    gload_lds16(asrc1 + BK,   &As[1][(64+w*16)*32]);
    LDB(s2_0,s2_1,s2_2,s2_3, 2, HIDDEN);
    gload_lds16(asrc0 + 2*BK, &As[2][(w*16)*32]);
    gload_lds16(asrc1 + 2*BK, &As[2][(64+w*16)*32]);
    asm volatile("s_waitcnt vmcnt(12)" ::: "memory");
    WRB0(s0_0,s0_1,s0_2,s0_3);
    asm volatile("s_waitcnt lgkmcnt(0)" ::: "memory");
    __builtin_amdgcn_s_barrier();

    int aR=0, aW=3, bRd=0;
    for (int k3=0; k3<NK2; k3+=3){
        PSTEP(k3,   NK2, HIDDEN, s0_0,s0_1,s0_2,s0_3, s1_0,s1_1,s1_2,s1_3);
        PSTEP(k3+1, NK2, HIDDEN, s1_0,s1_1,s1_2,s1_3, s2_0,s2_1,s2_2,s2_3);
        PSTEP(k3+2, NK2, HIDDEN, s2_0,s2_1,s2_2,s2_3, s0_0,s0_1,s0_2,s0_3);
    }
    asm volatile("s_waitcnt vmcnt(0)" ::: "memory");

    const int rbase = w*32 + kb*4;
#pragma unroll
    for (int mr=0;mr<2;mr++){
#pragma unroll
        for (int qq=0;qq<4;qq++){
            int row = rbase + mr*16 + qq;
            if (row < rows){
                float* orow = out + (size_t)s_tok[row]*HIDDEN + n0 + l15;
#pragma unroll
                for (int c=0;c<8;c++)
                    atomicAdd(orow + c*16, acc[mr][c][qq]);
            }
        }
    }
}

/* ---------------- host launch ---------------- */
extern "C" void kernel_launch(void* const* d_in, const int* in_sizes, int n_in,
                              void* d_out, int out_size, void* d_ws, size_t ws_size,
                              hipStream_t stream){
    const float* x    = (const float*)d_in[0];
    const float* gate = (const float*)d_in[1];
    const float* gup  = (const float*)d_in[2];
    const float* down = (const float*)d_in[3];
    float* out = (float*)d_out;
    char*  ws  = (char*)d_ws;

    int*   topk_id  = (int*)  (ws + 0x00000);
    float* topk_w   = (float*)(ws + 0x08000);
    int*   counts   = (int*)  (ws + 0x10000);
    int*   cursors  = (int*)  (ws + 0x10080);
    int*   offs     = (int*)  (ws + 0x10100);
    int*   nmt      = (int*)  (ws + 0x10180);
    int*   te       = (int*)  (ws + 0x10200);
    int*   tr0      = (int*)  (ws + 0x10400);
    int*   trn      = (int*)  (ws + 0x10600);
    int*   pair_tok = (int*)  (ws + 0x10800);
    float* pair_w   = (float*)(ws + 0x18800);
    unsigned short* gated = (unsigned short*)(ws + 0x21000);    // 8192*768*2 = 12.6MB
    unsigned short* xb    = (unsigned short*)(ws + 0xC60000);   // 2048*2048*2 = 8MB

    hipMemsetAsync(d_out, 0, (size_t)out_size*sizeof(float), stream);
    hipMemsetAsync(counts, 0, NEXPERT*sizeof(int), stream);

    cvt_x_k  <<<T_TOKENS*HIDDEN/(256*8), 256, 0, stream>>>(x, xb);
    router_k <<<T_TOKENS, 64, 0, stream>>>(x, gate, topk_id, topk_w, counts);
    sched_k  <<<1, 64, 0, stream>>>(counts, offs, cursors, nmt, te, tr0, trn);
    scatter_k<<<NPAIRS/256, 256, 0, stream>>>(topk_id, topk_w, cursors, pair_tok, pair_w);
    gemm1_k  <<<MT_MAX*NT1, 256, 0, stream>>>(xb, gup, nmt, te, tr0, trn, pair_tok, pair_w, gated);
    gemm2_k  <<<MT_MAX*NT2, 256, 0, stream>>>(gated, down, nmt, te, tr0, trn, pair_tok, out);
}